// Round 3
// baseline (372.250 us; speedup 1.0000x reference)
//
#include <hip/hip_runtime.h>
#include <hip/hip_bf16.h>

#define N_NODES    100000
#define N_EDGES    1600000
#define NODE_DIM   128
#define EDGE_DIM   32
#define GLOBAL_DIM 64
#define HIDDEN_DIM 256
#define N_GRAPHS   512
#define IN_DIM     224   // 128 + 32 + 64

#define NSLOT      64    // edge accumulator copies (contention spreading)
#define NODE_BLKS  1024
#define NODE_WAVES (NODE_BLKS * 4)
#define EDGE_BLKS  256   // one 1024-thread block per CU
#define EDGE_CH    (N_EDGES / EDGE_BLKS)   // 6250

// ---------------- workspace layout (float-sized units) ----------------
#define WS_NSUM  0
#define WS_NCNT  (WS_NSUM + N_GRAPHS * NODE_DIM)            // 65536
#define WS_ECNT  (WS_NCNT + N_GRAPHS)                       // 66048 (uint32)
#define WS_ESLOT (WS_ECNT + N_GRAPHS)                       // 66560
#define WS_ZERO  (WS_ESLOT + NSLOT * N_GRAPHS * EDGE_DIM)   // 1115136 — zero everything before this
#define WS_FEAT  WS_ZERO
#define WS_SEG   (WS_FEAT + N_GRAPHS * IN_DIM)              // 1229824 (ushort array)

// ---------------- node scatter-sum (batch sorted: run-length in regs) ------
__global__ __launch_bounds__(256) void node_scatter(const float* __restrict__ x,
                                                    const int* __restrict__ batch,
                                                    float* __restrict__ nsum,
                                                    float* __restrict__ ncnt) {
    int w = (blockIdx.x * blockDim.x + threadIdx.x) >> 6;
    int lane = threadIdx.x & 63;
    const int CH = (N_NODES + NODE_WAVES - 1) / NODE_WAVES;  // 25
    int s = w * CH;
    int e = min(s + CH, N_NODES);
    if (s >= e) return;

    float ax = 0.f, ay = 0.f;
    int cur = batch[s];
    int run = 0;
    for (int i = s; i < e; ++i) {
        int b = batch[i];
        if (b != cur) {
            atomicAdd(&nsum[cur * NODE_DIM + lane * 2 + 0], ax);
            atomicAdd(&nsum[cur * NODE_DIM + lane * 2 + 1], ay);
            if (lane == 0) atomicAdd(&ncnt[cur], (float)run);
            ax = ay = 0.f; run = 0; cur = b;
        }
        const float2 v = *reinterpret_cast<const float2*>(x + (size_t)i * NODE_DIM + lane * 2);
        ax += v.x; ay += v.y; ++run;
    }
    atomicAdd(&nsum[cur * NODE_DIM + lane * 2 + 0], ax);
    atomicAdd(&nsum[cur * NODE_DIM + lane * 2 + 1], ay);
    if (lane == 0) atomicAdd(&ncnt[cur], (float)run);
}

// ---------------- phase A: seg[e] = batch[eidx[e]] + per-graph edge counts -
__global__ __launch_bounds__(256) void edge_seg(const int* __restrict__ eidx,
                                                const int* __restrict__ batch,
                                                unsigned short* __restrict__ seg,
                                                unsigned int* __restrict__ ecnt) {
    __shared__ unsigned int hist[N_GRAPHS];
    for (int i = threadIdx.x; i < N_GRAPHS; i += 256) hist[i] = 0;
    __syncthreads();

    int base = (blockIdx.x * 256 + threadIdx.x) * 4;
    if (base < N_EDGES) {
        const int4 e4 = *reinterpret_cast<const int4*>(eidx + base);
        int s0 = batch[e4.x];
        int s1 = batch[e4.y];
        int s2 = batch[e4.z];
        int s3 = batch[e4.w];
        ushort4 sv;
        sv.x = (unsigned short)s0; sv.y = (unsigned short)s1;
        sv.z = (unsigned short)s2; sv.w = (unsigned short)s3;
        *reinterpret_cast<ushort4*>(seg + base) = sv;
        atomicAdd(&hist[s0], 1u);
        atomicAdd(&hist[s1], 1u);
        atomicAdd(&hist[s2], 1u);
        atomicAdd(&hist[s3], 1u);
    }
    __syncthreads();
    for (int i = threadIdx.x; i < N_GRAPHS; i += 256)
        if (hist[i]) atomicAdd(&ecnt[i], hist[i]);
}

// ---------------- phase B: edge scatter-sum (LDS histogram, stride 33) -----
__global__ __launch_bounds__(1024) void edge_scatter(const float* __restrict__ eattr,
                                                     const unsigned short* __restrict__ seg,
                                                     float* __restrict__ eslot) {
    __shared__ float ssum[N_GRAPHS * 33];   // stride 33: bank = (seg+dim)%32
    for (int i = threadIdx.x; i < N_GRAPHS * 33; i += 1024) ssum[i] = 0.f;
    __syncthreads();

    const int p = threadIdx.x & 7;          // 8 lanes per 32-float edge row
    const int e1 = blockIdx.x * EDGE_CH + EDGE_CH;
#pragma unroll 2
    for (int e = blockIdx.x * EDGE_CH + (threadIdx.x >> 3); e < e1; e += 128) {
        int s = seg[e];
        const float4 v = *reinterpret_cast<const float4*>(eattr + (size_t)e * EDGE_DIM + p * 4);
        float* row = ssum + s * 33 + p * 4;
        atomicAdd(row + 0, v.x);
        atomicAdd(row + 1, v.y);
        atomicAdd(row + 2, v.z);
        atomicAdd(row + 3, v.w);
    }
    __syncthreads();

    float* gs = eslot + (size_t)(blockIdx.x & (NSLOT - 1)) * (N_GRAPHS * EDGE_DIM);
    for (int i = threadIdx.x; i < N_GRAPHS * EDGE_DIM; i += 1024)
        atomicAdd(gs + i, ssum[(i >> 5) * 33 + (i & 31)]);
}

// ---------------- finalize: means + concat [node_mean | edge_mean | u] -----
__global__ __launch_bounds__(256) void finalize_feat(const float* __restrict__ nsum,
                                                     const float* __restrict__ ncnt,
                                                     const float* __restrict__ eslot,
                                                     const unsigned int* __restrict__ ecnt,
                                                     const float* __restrict__ u,
                                                     float* __restrict__ feat) {
    int g = blockIdx.x;
    int t = threadIdx.x;
    __shared__ float s_nc, s_ec;
    if (t == 0) {
        s_nc = fmaxf(ncnt[g], 1.f);
        s_ec = fmaxf((float)ecnt[g], 1.f);
    }
    __syncthreads();
    if (t < NODE_DIM) {
        feat[g * IN_DIM + t] = nsum[g * NODE_DIM + t] / s_nc;
    } else if (t < NODE_DIM + EDGE_DIM) {
        int d = t - NODE_DIM;
        float s = 0.f;
#pragma unroll 8
        for (int sl = 0; sl < NSLOT; ++sl)
            s += eslot[(size_t)sl * (N_GRAPHS * EDGE_DIM) + g * EDGE_DIM + d];
        feat[g * IN_DIM + t] = s / s_ec;
    } else if (t < IN_DIM) {
        feat[g * IN_DIM + t] = u[g * GLOBAL_DIM + (t - NODE_DIM - EDGE_DIM)];
    }
}

// ---------------- 3-layer MLP: one block per graph -------------------------
__global__ __launch_bounds__(256) void mlp_kernel(const float* __restrict__ feat,
                                                  const float* __restrict__ W1, const float* __restrict__ b1,
                                                  const float* __restrict__ W2, const float* __restrict__ b2,
                                                  const float* __restrict__ W3, const float* __restrict__ b3,
                                                  float* __restrict__ out) {
    int g = blockIdx.x;
    int j = threadIdx.x;
    __shared__ float h[HIDDEN_DIM];
    __shared__ float h2[HIDDEN_DIM];
    __shared__ float red[256];

    const float* f = feat + g * IN_DIM;
    float acc = b1[j];
#pragma unroll 4
    for (int k = 0; k < IN_DIM; ++k) acc = fmaf(f[k], W1[k * HIDDEN_DIM + j], acc);
    h[j] = fmaxf(acc, 0.f);
    __syncthreads();

    float acc2 = b2[j];
#pragma unroll 4
    for (int k = 0; k < HIDDEN_DIM; ++k) acc2 = fmaf(h[k], W2[k * HIDDEN_DIM + j], acc2);
    h2[j] = fmaxf(acc2, 0.f);
    __syncthreads();

    int col = j & 63;
    int q = j >> 6;
    float acc3 = 0.f;
#pragma unroll 4
    for (int k = q * 64; k < q * 64 + 64; ++k) acc3 = fmaf(h2[k], W3[k * GLOBAL_DIM + col], acc3);
    red[j] = acc3;
    __syncthreads();
    if (j < GLOBAL_DIM) {
        out[g * GLOBAL_DIM + j] = red[j] + red[j + 64] + red[j + 128] + red[j + 192] + b3[j];
    }
}

extern "C" void kernel_launch(void* const* d_in, const int* in_sizes, int n_in,
                              void* d_out, int out_size, void* d_ws, size_t ws_size,
                              hipStream_t stream) {
    const float* x         = (const float*)d_in[0];
    const int*   edge_idx  = (const int*)d_in[1];    // [2, E]; first E = sources
    const float* edge_attr = (const float*)d_in[2];
    const float* u         = (const float*)d_in[3];
    const int*   batch     = (const int*)d_in[4];
    const float* W1 = (const float*)d_in[5];
    const float* b1 = (const float*)d_in[6];
    const float* W2 = (const float*)d_in[7];
    const float* b2 = (const float*)d_in[8];
    const float* W3 = (const float*)d_in[9];
    const float* b3 = (const float*)d_in[10];
    float* out = (float*)d_out;

    float* ws = (float*)d_ws;
    float*          nsum  = ws + WS_NSUM;
    float*          ncnt  = ws + WS_NCNT;
    unsigned int*   ecnt  = (unsigned int*)(ws + WS_ECNT);
    float*          eslot = ws + WS_ESLOT;
    float*          feat  = ws + WS_FEAT;
    unsigned short* seg   = (unsigned short*)(ws + WS_SEG);

    // zero the accumulators (graph replays reuse ws — atomics would accumulate)
    hipMemsetAsync(d_ws, 0, (size_t)WS_ZERO * sizeof(float), stream);

    edge_seg<<<(N_EDGES / 4 + 255) / 256, 256, 0, stream>>>(edge_idx, batch, seg, ecnt);
    node_scatter<<<NODE_BLKS, 256, 0, stream>>>(x, batch, nsum, ncnt);
    edge_scatter<<<EDGE_BLKS, 1024, 0, stream>>>(edge_attr, seg, eslot);
    finalize_feat<<<N_GRAPHS, 256, 0, stream>>>(nsum, ncnt, eslot, ecnt, u, feat);
    mlp_kernel<<<N_GRAPHS, 256, 0, stream>>>(feat, W1, b1, W2, b2, W3, b3, out);
}

// Round 4
// 147.124 us; speedup vs baseline: 2.5302x; 2.5302x over previous
//
#include <hip/hip_runtime.h>
#include <hip/hip_bf16.h>

#define N_NODES    100000
#define N_EDGES    1600000
#define NODE_DIM   128
#define EDGE_DIM   32
#define GLOBAL_DIM 64
#define HIDDEN_DIM 256
#define N_GRAPHS   512
#define IN_DIM     224   // 128 + 32 + 64

#define NSLOT      64    // edge accumulator copies (contention spreading)
#define NODE_BLKS  1024
#define NODE_WAVES (NODE_BLKS * 4)
#define EDGE_BLKS  256   // one 1024-thread block per CU
#define EDGE_CH    (N_EDGES / EDGE_BLKS)   // 6250

// fixed-point scale for int32 accumulation (native atomics; fp32 atomicAdd
// compiles to a CAS loop on HIP without -munsafe-fp-atomics — round-3 lesson)
#define FXS   1048576.0f          // 2^20
#define FXINV (1.0f / 1048576.0f)

// ---------------- workspace layout (4-byte units) ----------------
#define WS_NSUM  0                                          // int[512*128]
#define WS_NCNT  (WS_NSUM + N_GRAPHS * NODE_DIM)            // int[512]
#define WS_ECNT  (WS_NCNT + N_GRAPHS)                       // uint[512]
#define WS_ESLOT (WS_ECNT + N_GRAPHS)                       // int[64*512*32]
#define WS_ZERO  (WS_ESLOT + NSLOT * N_GRAPHS * EDGE_DIM)   // zero everything before this
#define WS_FEAT  WS_ZERO                                    // float[512*224]
#define WS_SEG   (WS_FEAT + N_GRAPHS * IN_DIM)              // ushort[1.6M]

// ---------------- node scatter-sum (batch sorted: run-length in regs) ------
__global__ __launch_bounds__(256) void node_scatter(const float* __restrict__ x,
                                                    const int* __restrict__ batch,
                                                    int* __restrict__ nsum,
                                                    int* __restrict__ ncnt) {
    int w = (blockIdx.x * blockDim.x + threadIdx.x) >> 6;
    int lane = threadIdx.x & 63;
    const int CH = (N_NODES + NODE_WAVES - 1) / NODE_WAVES;  // 25
    int s = w * CH;
    int e = min(s + CH, N_NODES);
    if (s >= e) return;

    float ax = 0.f, ay = 0.f;
    int cur = batch[s];
    int run = 0;
    for (int i = s; i < e; ++i) {
        int b = batch[i];
        if (b != cur) {
            atomicAdd(&nsum[cur * NODE_DIM + lane * 2 + 0], __float2int_rn(ax * FXS));
            atomicAdd(&nsum[cur * NODE_DIM + lane * 2 + 1], __float2int_rn(ay * FXS));
            if (lane == 0) atomicAdd(&ncnt[cur], run);
            ax = ay = 0.f; run = 0; cur = b;
        }
        const float2 v = *reinterpret_cast<const float2*>(x + (size_t)i * NODE_DIM + lane * 2);
        ax += v.x; ay += v.y; ++run;
    }
    atomicAdd(&nsum[cur * NODE_DIM + lane * 2 + 0], __float2int_rn(ax * FXS));
    atomicAdd(&nsum[cur * NODE_DIM + lane * 2 + 1], __float2int_rn(ay * FXS));
    if (lane == 0) atomicAdd(&ncnt[cur], run);
}

// ---------------- phase A: seg[e] = batch[eidx[e]] + per-graph edge counts -
__global__ __launch_bounds__(256) void edge_seg(const int* __restrict__ eidx,
                                                const int* __restrict__ batch,
                                                unsigned short* __restrict__ seg,
                                                unsigned int* __restrict__ ecnt) {
    __shared__ unsigned int hist[N_GRAPHS];
    for (int i = threadIdx.x; i < N_GRAPHS; i += 256) hist[i] = 0;
    __syncthreads();

    int base = (blockIdx.x * 256 + threadIdx.x) * 4;
    if (base < N_EDGES) {
        const int4 e4 = *reinterpret_cast<const int4*>(eidx + base);
        int s0 = batch[e4.x];
        int s1 = batch[e4.y];
        int s2 = batch[e4.z];
        int s3 = batch[e4.w];
        ushort4 sv;
        sv.x = (unsigned short)s0; sv.y = (unsigned short)s1;
        sv.z = (unsigned short)s2; sv.w = (unsigned short)s3;
        *reinterpret_cast<ushort4*>(seg + base) = sv;
        atomicAdd(&hist[s0], 1u);
        atomicAdd(&hist[s1], 1u);
        atomicAdd(&hist[s2], 1u);
        atomicAdd(&hist[s3], 1u);
    }
    __syncthreads();
    for (int i = threadIdx.x; i < N_GRAPHS; i += 256)
        if (hist[i]) atomicAdd(&ecnt[i], hist[i]);
}

// ---------------- phase B: edge scatter-sum (int LDS histogram, stride 33) -
__global__ __launch_bounds__(1024) void edge_scatter(const float* __restrict__ eattr,
                                                     const unsigned short* __restrict__ seg,
                                                     int* __restrict__ eslot) {
    __shared__ int ssum[N_GRAPHS * 33];   // stride 33: bank = (seg+dim)%32
    for (int i = threadIdx.x; i < N_GRAPHS * 33; i += 1024) ssum[i] = 0;
    __syncthreads();

    const int p = threadIdx.x & 7;          // 8 lanes per 32-float edge row
    const int e1 = blockIdx.x * EDGE_CH + EDGE_CH;
#pragma unroll 2
    for (int e = blockIdx.x * EDGE_CH + (threadIdx.x >> 3); e < e1; e += 128) {
        int s = seg[e];
        const float4 v = *reinterpret_cast<const float4*>(eattr + (size_t)e * EDGE_DIM + p * 4);
        const int b = s * 33 + p * 4;
        atomicAdd(&ssum[b + 0], __float2int_rn(v.x * FXS));
        atomicAdd(&ssum[b + 1], __float2int_rn(v.y * FXS));
        atomicAdd(&ssum[b + 2], __float2int_rn(v.z * FXS));
        atomicAdd(&ssum[b + 3], __float2int_rn(v.w * FXS));
    }
    __syncthreads();

    int* gs = eslot + (size_t)(blockIdx.x & (NSLOT - 1)) * (N_GRAPHS * EDGE_DIM);
    for (int i = threadIdx.x; i < N_GRAPHS * EDGE_DIM; i += 1024) {
        int v = ssum[(i >> 5) * 33 + (i & 31)];
        if (v != 0) atomicAdd(gs + i, v);
    }
}

// ---------------- finalize: means + concat [node_mean | edge_mean | u] -----
__global__ __launch_bounds__(256) void finalize_feat(const int* __restrict__ nsum,
                                                     const int* __restrict__ ncnt,
                                                     const int* __restrict__ eslot,
                                                     const unsigned int* __restrict__ ecnt,
                                                     const float* __restrict__ u,
                                                     float* __restrict__ feat) {
    int g = blockIdx.x;
    int t = threadIdx.x;
    __shared__ float s_nc, s_ec;
    if (t == 0) {
        s_nc = fmaxf((float)ncnt[g], 1.f);
        s_ec = fmaxf((float)ecnt[g], 1.f);
    }
    __syncthreads();
    if (t < NODE_DIM) {
        feat[g * IN_DIM + t] = ((float)nsum[g * NODE_DIM + t] * FXINV) / s_nc;
    } else if (t < NODE_DIM + EDGE_DIM) {
        int d = t - NODE_DIM;
        long long sll = 0;
#pragma unroll 8
        for (int sl = 0; sl < NSLOT; ++sl)
            sll += eslot[(size_t)sl * (N_GRAPHS * EDGE_DIM) + g * EDGE_DIM + d];
        feat[g * IN_DIM + t] = ((float)sll * FXINV) / s_ec;
    } else if (t < IN_DIM) {
        feat[g * IN_DIM + t] = u[g * GLOBAL_DIM + (t - NODE_DIM - EDGE_DIM)];
    }
}

// ---------------- 3-layer MLP: one block per graph -------------------------
__global__ __launch_bounds__(256) void mlp_kernel(const float* __restrict__ feat,
                                                  const float* __restrict__ W1, const float* __restrict__ b1,
                                                  const float* __restrict__ W2, const float* __restrict__ b2,
                                                  const float* __restrict__ W3, const float* __restrict__ b3,
                                                  float* __restrict__ out) {
    int g = blockIdx.x;
    int j = threadIdx.x;
    __shared__ float h[HIDDEN_DIM];
    __shared__ float h2[HIDDEN_DIM];
    __shared__ float red[256];

    const float* f = feat + g * IN_DIM;
    float acc = b1[j];
#pragma unroll 4
    for (int k = 0; k < IN_DIM; ++k) acc = fmaf(f[k], W1[k * HIDDEN_DIM + j], acc);
    h[j] = fmaxf(acc, 0.f);
    __syncthreads();

    float acc2 = b2[j];
#pragma unroll 4
    for (int k = 0; k < HIDDEN_DIM; ++k) acc2 = fmaf(h[k], W2[k * HIDDEN_DIM + j], acc2);
    h2[j] = fmaxf(acc2, 0.f);
    __syncthreads();

    int col = j & 63;
    int q = j >> 6;
    float acc3 = 0.f;
#pragma unroll 4
    for (int k = q * 64; k < q * 64 + 64; ++k) acc3 = fmaf(h2[k], W3[k * GLOBAL_DIM + col], acc3);
    red[j] = acc3;
    __syncthreads();
    if (j < GLOBAL_DIM) {
        out[g * GLOBAL_DIM + j] = red[j] + red[j + 64] + red[j + 128] + red[j + 192] + b3[j];
    }
}

extern "C" void kernel_launch(void* const* d_in, const int* in_sizes, int n_in,
                              void* d_out, int out_size, void* d_ws, size_t ws_size,
                              hipStream_t stream) {
    const float* x         = (const float*)d_in[0];
    const int*   edge_idx  = (const int*)d_in[1];    // [2, E]; first E = sources
    const float* edge_attr = (const float*)d_in[2];
    const float* u         = (const float*)d_in[3];
    const int*   batch     = (const int*)d_in[4];
    const float* W1 = (const float*)d_in[5];
    const float* b1 = (const float*)d_in[6];
    const float* W2 = (const float*)d_in[7];
    const float* b2 = (const float*)d_in[8];
    const float* W3 = (const float*)d_in[9];
    const float* b3 = (const float*)d_in[10];
    float* out = (float*)d_out;

    int* ws32 = (int*)d_ws;
    int*            nsum  = ws32 + WS_NSUM;
    int*            ncnt  = ws32 + WS_NCNT;
    unsigned int*   ecnt  = (unsigned int*)(ws32 + WS_ECNT);
    int*            eslot = ws32 + WS_ESLOT;
    float*          feat  = (float*)(ws32 + WS_FEAT);
    unsigned short* seg   = (unsigned short*)(ws32 + WS_SEG);

    // zero the accumulators (graph replays reuse ws — atomics would accumulate)
    hipMemsetAsync(d_ws, 0, (size_t)WS_ZERO * 4, stream);

    edge_seg<<<(N_EDGES / 4 + 255) / 256, 256, 0, stream>>>(edge_idx, batch, seg, ecnt);
    node_scatter<<<NODE_BLKS, 256, 0, stream>>>(x, batch, nsum, ncnt);
    edge_scatter<<<EDGE_BLKS, 1024, 0, stream>>>(edge_attr, seg, eslot);
    finalize_feat<<<N_GRAPHS, 256, 0, stream>>>(nsum, ncnt, eslot, ecnt, u, feat);
    mlp_kernel<<<N_GRAPHS, 256, 0, stream>>>(feat, W1, b1, W2, b2, W3, b3, out);
}

// Round 5
// 132.028 us; speedup vs baseline: 2.8195x; 1.1143x over previous
//
#include <hip/hip_runtime.h>
#include <hip/hip_bf16.h>

#define N_NODES    100000
#define N_EDGES    1600000
#define NODE_DIM   128
#define EDGE_DIM   32
#define GLOBAL_DIM 64
#define HIDDEN_DIM 256
#define N_GRAPHS   512
#define IN_DIM     224   // 128 + 32 + 64

#define NODE_BLKS  1024
#define NODE_WAVES (NODE_BLKS * 4)
#define EDGE_BLKS  256   // one 1024-thread block per CU; also the slot count
#define EDGE_CH    (N_EDGES / EDGE_BLKS)   // 6250
#define GPB        4     // graphs per MLP block

// fixed-point scale for int32 accumulation (native atomics; fp32 atomicAdd
// compiles to a CAS loop on HIP without -munsafe-fp-atomics — round-3 lesson)
#define FXS   1048576.0f          // 2^20
#define FXINV (1.0f / 1048576.0f)

// ---------------- workspace layout (4-byte units) ----------------
#define WS_NSUM  0                                          // int[512*128]
#define WS_NCNT  (WS_NSUM + N_GRAPHS * NODE_DIM)            // int[512]
#define WS_ECNT  (WS_NCNT + N_GRAPHS)                       // uint[512]
#define WS_ZERO  (WS_ECNT + N_GRAPHS)                       // 66560 — zero everything before this
#define WS_ESLOT WS_ZERO                                    // int[256*512*32] — fully written, no zero needed
#define WS_FEAT  (WS_ESLOT + EDGE_BLKS * N_GRAPHS * EDGE_DIM) // float[512*224]
#define WS_SEG   (WS_FEAT + N_GRAPHS * IN_DIM)              // ushort[1.6M]

// ---------------- tiny zero kernel (round-4 lesson: rocclr small fill = 118 µs!) --
__global__ __launch_bounds__(256) void zero_small(int4* __restrict__ p, int n4) {
    int i = blockIdx.x * 256 + threadIdx.x;
    if (i < n4) p[i] = int4{0, 0, 0, 0};
}

// ---------------- node scatter-sum (batch sorted: run-length in regs) ------
__global__ __launch_bounds__(256) void node_scatter(const float* __restrict__ x,
                                                    const int* __restrict__ batch,
                                                    int* __restrict__ nsum,
                                                    int* __restrict__ ncnt) {
    int w = (blockIdx.x * blockDim.x + threadIdx.x) >> 6;
    int lane = threadIdx.x & 63;
    const int CH = (N_NODES + NODE_WAVES - 1) / NODE_WAVES;  // 25
    int s = w * CH;
    int e = min(s + CH, N_NODES);
    if (s >= e) return;

    float ax = 0.f, ay = 0.f;
    int cur = batch[s];
    int run = 0;
    for (int i = s; i < e; ++i) {
        int b = batch[i];
        if (b != cur) {
            atomicAdd(&nsum[cur * NODE_DIM + lane * 2 + 0], __float2int_rn(ax * FXS));
            atomicAdd(&nsum[cur * NODE_DIM + lane * 2 + 1], __float2int_rn(ay * FXS));
            if (lane == 0) atomicAdd(&ncnt[cur], run);
            ax = ay = 0.f; run = 0; cur = b;
        }
        const float2 v = *reinterpret_cast<const float2*>(x + (size_t)i * NODE_DIM + lane * 2);
        ax += v.x; ay += v.y; ++run;
    }
    atomicAdd(&nsum[cur * NODE_DIM + lane * 2 + 0], __float2int_rn(ax * FXS));
    atomicAdd(&nsum[cur * NODE_DIM + lane * 2 + 1], __float2int_rn(ay * FXS));
    if (lane == 0) atomicAdd(&ncnt[cur], run);
}

// ---------------- phase A: seg[e] = batch[eidx[e]] + per-graph edge counts -
__global__ __launch_bounds__(256) void edge_seg(const int* __restrict__ eidx,
                                                const int* __restrict__ batch,
                                                unsigned short* __restrict__ seg,
                                                unsigned int* __restrict__ ecnt) {
    __shared__ unsigned int hist[N_GRAPHS];
    for (int i = threadIdx.x; i < N_GRAPHS; i += 256) hist[i] = 0;
    __syncthreads();

    int base = (blockIdx.x * 256 + threadIdx.x) * 4;
    if (base < N_EDGES) {
        const int4 e4 = *reinterpret_cast<const int4*>(eidx + base);
        int s0 = batch[e4.x];
        int s1 = batch[e4.y];
        int s2 = batch[e4.z];
        int s3 = batch[e4.w];
        ushort4 sv;
        sv.x = (unsigned short)s0; sv.y = (unsigned short)s1;
        sv.z = (unsigned short)s2; sv.w = (unsigned short)s3;
        *reinterpret_cast<ushort4*>(seg + base) = sv;
        atomicAdd(&hist[s0], 1u);
        atomicAdd(&hist[s1], 1u);
        atomicAdd(&hist[s2], 1u);
        atomicAdd(&hist[s3], 1u);
    }
    __syncthreads();
    for (int i = threadIdx.x; i < N_GRAPHS; i += 256)
        if (hist[i]) atomicAdd(&ecnt[i], hist[i]);
}

// ---------------- phase B: edge scatter-sum (int LDS histogram, stride 33) -
// Flush: PLAIN stores to block-private slot (no zero-init, no global atomics).
__global__ __launch_bounds__(1024) void edge_scatter(const float* __restrict__ eattr,
                                                     const unsigned short* __restrict__ seg,
                                                     int* __restrict__ eslot) {
    __shared__ int ssum[N_GRAPHS * 33];   // stride 33: bank = (seg+dim)%32
    for (int i = threadIdx.x; i < N_GRAPHS * 33; i += 1024) ssum[i] = 0;
    __syncthreads();

    const int p = threadIdx.x & 7;          // 8 lanes per 32-float edge row
    const int e1 = blockIdx.x * EDGE_CH + EDGE_CH;
#pragma unroll 2
    for (int e = blockIdx.x * EDGE_CH + (threadIdx.x >> 3); e < e1; e += 128) {
        int s = seg[e];
        const float4 v = *reinterpret_cast<const float4*>(eattr + (size_t)e * EDGE_DIM + p * 4);
        const int b = s * 33 + p * 4;
        atomicAdd(&ssum[b + 0], __float2int_rn(v.x * FXS));
        atomicAdd(&ssum[b + 1], __float2int_rn(v.y * FXS));
        atomicAdd(&ssum[b + 2], __float2int_rn(v.z * FXS));
        atomicAdd(&ssum[b + 3], __float2int_rn(v.w * FXS));
    }
    __syncthreads();

    int* gs = eslot + (size_t)blockIdx.x * (N_GRAPHS * EDGE_DIM);
    for (int i = threadIdx.x; i < N_GRAPHS * EDGE_DIM; i += 1024)
        gs[i] = ssum[(i >> 5) * 33 + (i & 31)];
}

// ---------------- finalize: slot-reduce + means + concat -------------------
__global__ __launch_bounds__(256) void finalize_feat(const int* __restrict__ nsum,
                                                     const int* __restrict__ ncnt,
                                                     const int* __restrict__ eslot,
                                                     const unsigned int* __restrict__ ecnt,
                                                     const float* __restrict__ u,
                                                     float* __restrict__ feat) {
    int g = blockIdx.x;
    int t = threadIdx.x;
    __shared__ int red[256];
    __shared__ float s_nc, s_ec;

    // all 256 threads: 8 partials per dim over the 256 slots
    const int d = t & 31, part = t >> 5;
    int partial = 0;
#pragma unroll 8
    for (int sl = part * 32; sl < part * 32 + 32; ++sl)
        partial += eslot[(size_t)sl * (N_GRAPHS * EDGE_DIM) + g * EDGE_DIM + d];
    red[t] = partial;
    if (t == 0) {
        s_nc = fmaxf((float)ncnt[g], 1.f);
        s_ec = fmaxf((float)ecnt[g], 1.f);
    }
    __syncthreads();

    if (t < NODE_DIM) {
        feat[g * IN_DIM + t] = ((float)nsum[g * NODE_DIM + t] * FXINV) / s_nc;
    } else if (t < NODE_DIM + EDGE_DIM) {
        int dd = t - NODE_DIM;
        int s = red[dd] + red[dd + 32] + red[dd + 64] + red[dd + 96] +
                red[dd + 128] + red[dd + 160] + red[dd + 192] + red[dd + 224];
        feat[g * IN_DIM + t] = ((float)s * FXINV) / s_ec;
    } else if (t < IN_DIM) {
        feat[g * IN_DIM + t] = u[g * GLOBAL_DIM + (t - NODE_DIM - EDGE_DIM)];
    }
}

// ---------------- 3-layer MLP: GPB graphs per block (weight reuse) ---------
__global__ __launch_bounds__(256) void mlp_kernel(const float* __restrict__ feat,
                                                  const float* __restrict__ W1, const float* __restrict__ b1,
                                                  const float* __restrict__ W2, const float* __restrict__ b2,
                                                  const float* __restrict__ W3, const float* __restrict__ b3,
                                                  float* __restrict__ out) {
    const int g0 = blockIdx.x * GPB;
    const int j = threadIdx.x;
    __shared__ float fs[GPB * IN_DIM];        // 3.6 KB
    __shared__ float h[GPB][HIDDEN_DIM];      // 4 KB
    __shared__ float h2[GPB][HIDDEN_DIM];     // 4 KB
    __shared__ float red[GPB][256];           // 4 KB

    for (int i = j; i < GPB * IN_DIM; i += 256) fs[i] = feat[g0 * IN_DIM + i];
    __syncthreads();

    float acc[GPB];
    const float bb1 = b1[j];
#pragma unroll
    for (int g = 0; g < GPB; ++g) acc[g] = bb1;
    for (int k = 0; k < IN_DIM; ++k) {
        const float w = W1[k * HIDDEN_DIM + j];
#pragma unroll
        for (int g = 0; g < GPB; ++g) acc[g] = fmaf(fs[g * IN_DIM + k], w, acc[g]);
    }
#pragma unroll
    for (int g = 0; g < GPB; ++g) h[g][j] = fmaxf(acc[g], 0.f);
    __syncthreads();

    const float bb2 = b2[j];
#pragma unroll
    for (int g = 0; g < GPB; ++g) acc[g] = bb2;
    for (int k = 0; k < HIDDEN_DIM; ++k) {
        const float w = W2[k * HIDDEN_DIM + j];
#pragma unroll
        for (int g = 0; g < GPB; ++g) acc[g] = fmaf(h[g][k], w, acc[g]);
    }
#pragma unroll
    for (int g = 0; g < GPB; ++g) h2[g][j] = fmaxf(acc[g], 0.f);
    __syncthreads();

    // layer 3: 64 cols; thread j: col = j&63, k-quarter q = j>>6
    const int col = j & 63, q = j >> 6;
#pragma unroll
    for (int g = 0; g < GPB; ++g) acc[g] = 0.f;
    for (int k = q * 64; k < q * 64 + 64; ++k) {
        const float w = W3[k * GLOBAL_DIM + col];
#pragma unroll
        for (int g = 0; g < GPB; ++g) acc[g] = fmaf(h2[g][k], w, acc[g]);
    }
#pragma unroll
    for (int g = 0; g < GPB; ++g) red[g][j] = acc[g];
    __syncthreads();

    // threads 0..255: g = j>>6, col = j&63
    {
        const int g = j >> 6, c = j & 63;
        out[(g0 + g) * GLOBAL_DIM + c] = red[g][c] + red[g][c + 64] +
                                         red[g][c + 128] + red[g][c + 192] + b3[c];
    }
}

extern "C" void kernel_launch(void* const* d_in, const int* in_sizes, int n_in,
                              void* d_out, int out_size, void* d_ws, size_t ws_size,
                              hipStream_t stream) {
    const float* x         = (const float*)d_in[0];
    const int*   edge_idx  = (const int*)d_in[1];    // [2, E]; first E = sources
    const float* edge_attr = (const float*)d_in[2];
    const float* u         = (const float*)d_in[3];
    const int*   batch     = (const int*)d_in[4];
    const float* W1 = (const float*)d_in[5];
    const float* b1 = (const float*)d_in[6];
    const float* W2 = (const float*)d_in[7];
    const float* b2 = (const float*)d_in[8];
    const float* W3 = (const float*)d_in[9];
    const float* b3 = (const float*)d_in[10];
    float* out = (float*)d_out;

    int* ws32 = (int*)d_ws;
    int*            nsum  = ws32 + WS_NSUM;
    int*            ncnt  = ws32 + WS_NCNT;
    unsigned int*   ecnt  = (unsigned int*)(ws32 + WS_ECNT);
    int*            eslot = ws32 + WS_ESLOT;
    float*          feat  = (float*)(ws32 + WS_FEAT);
    unsigned short* seg   = (unsigned short*)(ws32 + WS_SEG);

    // zero only the atomic accumulators (266 KB) with our own kernel —
    // rocclr's fillBufferAligned for small sizes is latency-bound (118 µs!).
    const int n4 = WS_ZERO / 4;   // 16640 int4s
    zero_small<<<(n4 + 255) / 256, 256, 0, stream>>>((int4*)d_ws, n4);

    edge_seg<<<(N_EDGES / 4 + 255) / 256, 256, 0, stream>>>(edge_idx, batch, seg, ecnt);
    node_scatter<<<NODE_BLKS, 256, 0, stream>>>(x, batch, nsum, ncnt);
    edge_scatter<<<EDGE_BLKS, 1024, 0, stream>>>(edge_attr, seg, eslot);
    finalize_feat<<<N_GRAPHS, 256, 0, stream>>>(nsum, ncnt, eslot, ecnt, u, feat);
    mlp_kernel<<<N_GRAPHS / GPB, 256, 0, stream>>>(feat, W1, b1, W2, b2, W3, b3, out);
}

// Round 6
// 100.758 us; speedup vs baseline: 3.6945x; 1.3103x over previous
//
#include <hip/hip_runtime.h>
#include <hip/hip_bf16.h>

#define N_NODES    100000
#define N_EDGES    1600000
#define NODE_DIM   128
#define EDGE_DIM   32
#define GLOBAL_DIM 64
#define HIDDEN_DIM 256
#define N_GRAPHS   512
#define IN_DIM     224   // 128 + 32 + 64
#define ROW33      33    // 32 dims + count, stride-33 for bank spread

#define EDGE_BLKS  256                         // one 1024-thr block per CU; slot count
#define EDGE_CH    (N_EDGES / EDGE_BLKS)       // 6250
#define SEG_BLKS   ((N_EDGES / 4 + 255) / 256) // 1563
#define BND_BLKS   ((N_NODES + 255) / 256)     // 391
#define GPB        2                           // graphs per finalize+MLP block

// fixed-point scale for int32 LDS accumulation (fp32 atomicAdd = CAS loop on
// HIP without -munsafe-fp-atomics — round-3/4 lesson: int atomics are native)
#define FXS   1048576.0f          // 2^20
#define FXINV (1.0f / 1048576.0f)

// ---------------- workspace layout (4-byte units); NOTHING needs zeroing ---
#define WS_NSTART 0                                          // int[513] (pad 1024)
#define WS_NSUM   (WS_NSTART + 1024)                         // float[512*128]
#define WS_ESLOT  (WS_NSUM + N_GRAPHS * NODE_DIM)            // int[256*512*33]
#define WS_SEG    (WS_ESLOT + EDGE_BLKS * N_GRAPHS * ROW33)  // ushort[1.6M]

// ---------------- prep: seg[e] = batch[src[e]]  +  node run boundaries -----
__global__ __launch_bounds__(256) void prep(const int* __restrict__ eidx,
                                            const int* __restrict__ batch,
                                            unsigned short* __restrict__ seg,
                                            int* __restrict__ nstart) {
    const int blk = blockIdx.x;
    if (blk < SEG_BLKS) {
        const int base = (blk * 256 + threadIdx.x) * 4;
        if (base < N_EDGES) {
            const int4 e4 = *reinterpret_cast<const int4*>(eidx + base);
            ushort4 sv;
            sv.x = (unsigned short)batch[e4.x];
            sv.y = (unsigned short)batch[e4.y];
            sv.z = (unsigned short)batch[e4.z];
            sv.w = (unsigned short)batch[e4.w];
            *reinterpret_cast<ushort4*>(seg + base) = sv;
        }
    } else {
        const int i = (blk - SEG_BLKS) * 256 + threadIdx.x;
        if (i < N_NODES) {
            const int b0 = batch[i];
            if (i == 0)
                for (int g = 0; g <= b0; ++g) nstart[g] = 0;
            if (i < N_NODES - 1) {
                const int b1 = batch[i + 1];
                for (int g = b0 + 1; g <= b1; ++g) nstart[g] = i + 1;
            } else {
                for (int g = b0 + 1; g <= N_GRAPHS; ++g) nstart[g] = N_NODES;
            }
        }
    }
}

// ---------------- node range-sum: one block per graph, no atomics ----------
__global__ __launch_bounds__(256) void node_sum(const float* __restrict__ x,
                                                const int* __restrict__ nstart,
                                                float* __restrict__ nsum) {
    const int g = blockIdx.x, t = threadIdx.x;
    const int d = t & 127, half = t >> 7;      // 2 rows in flight per dim
    const int s0 = nstart[g], e0 = nstart[g + 1];

    float a0 = 0.f, a1 = 0.f, a2 = 0.f, a3 = 0.f;
    int r = s0 + half;
    for (; r + 6 < e0; r += 8) {               // 4 independent accumulators
        a0 += x[(size_t)(r    ) * NODE_DIM + d];
        a1 += x[(size_t)(r + 2) * NODE_DIM + d];
        a2 += x[(size_t)(r + 4) * NODE_DIM + d];
        a3 += x[(size_t)(r + 6) * NODE_DIM + d];
    }
    for (; r < e0; r += 2) a0 += x[(size_t)r * NODE_DIM + d];

    __shared__ float part[256];
    part[t] = (a0 + a1) + (a2 + a3);
    __syncthreads();
    if (t < 128) nsum[g * NODE_DIM + t] = part[t] + part[t + 128];
}

// ---------------- edge scatter-sum: int LDS histogram + count col ----------
__global__ __launch_bounds__(1024) void edge_scatter(const float* __restrict__ eattr,
                                                     const unsigned short* __restrict__ seg,
                                                     int* __restrict__ eslot) {
    __shared__ int ssum[N_GRAPHS * ROW33];     // 67.6 KB; bank = (s + dim) % 32
    for (int i = threadIdx.x; i < N_GRAPHS * ROW33; i += 1024) ssum[i] = 0;
    __syncthreads();

    const int p = threadIdx.x & 7;             // 8 lanes per 32-float edge row
    const int e1 = blockIdx.x * EDGE_CH + EDGE_CH;
#pragma unroll 4
    for (int e = blockIdx.x * EDGE_CH + (threadIdx.x >> 3); e < e1; e += 128) {
        const int s = seg[e];
        const float4 v = *reinterpret_cast<const float4*>(eattr + (size_t)e * EDGE_DIM + p * 4);
        const int b = s * ROW33 + p * 4;
        atomicAdd(&ssum[b + 0], __float2int_rn(v.x * FXS));
        atomicAdd(&ssum[b + 1], __float2int_rn(v.y * FXS));
        atomicAdd(&ssum[b + 2], __float2int_rn(v.z * FXS));
        atomicAdd(&ssum[b + 3], __float2int_rn(v.w * FXS));
        if (p == 0) atomicAdd(&ssum[s * ROW33 + 32], 1);
    }
    __syncthreads();

    // plain-store flush to block-private slot (no zero-init, no global atomics)
    int* gs = eslot + (size_t)blockIdx.x * (N_GRAPHS * ROW33);
    for (int i = threadIdx.x; i < N_GRAPHS * ROW33; i += 1024) gs[i] = ssum[i];
}

// ---------------- finalize + MLP fused: GPB graphs per block ---------------
__global__ __launch_bounds__(256) void finalize_mlp(const float* __restrict__ nsum,
                                                    const int* __restrict__ nstart,
                                                    const int* __restrict__ eslot,
                                                    const float* __restrict__ u,
                                                    const float* __restrict__ W1, const float* __restrict__ b1,
                                                    const float* __restrict__ W2, const float* __restrict__ b2,
                                                    const float* __restrict__ W3, const float* __restrict__ b3,
                                                    float* __restrict__ out) {
    const int g0 = blockIdx.x * GPB;
    const int t = threadIdx.x;
    __shared__ float fs[GPB * IN_DIM];
    __shared__ long long redll[256];
    __shared__ float h[GPB][HIDDEN_DIM];
    __shared__ float h2[GPB][HIDDEN_DIM];
    __shared__ float red[GPB][256];
    __shared__ float s_ecnt[GPB];

    // edge dim partials: col = t&63 (g = col>>5, d = col&31), part = t>>6 over 4x64 slots
    {
        const int col = t & 63, part = t >> 6;
        const int g = col >> 5, d = col & 31;
        long long s = 0;
#pragma unroll 8
        for (int sl = part * 64; sl < part * 64 + 64; ++sl)
            s += eslot[(size_t)sl * (N_GRAPHS * ROW33) + (size_t)(g0 + g) * ROW33 + d];
        redll[t] = s;
    }
    if (t < GPB) {  // edge counts (threads 0..1 scan all slots' count col)
        int c = 0;
#pragma unroll 8
        for (int sl = 0; sl < EDGE_BLKS; ++sl)
            c += eslot[(size_t)sl * (N_GRAPHS * ROW33) + (size_t)(g0 + t) * ROW33 + 32];
        s_ecnt[t] = fmaxf((float)c, 1.f);
    }
    __syncthreads();

    {   // node means: 2 graphs x 128 dims = 256 -> one per thread
        const int g = t >> 7, d = t & 127;
        const float cnt = fmaxf((float)(nstart[g0 + g + 1] - nstart[g0 + g]), 1.f);
        fs[g * IN_DIM + d] = nsum[(size_t)(g0 + g) * NODE_DIM + d] / cnt;
    }
    if (t < 64) {   // edge means: combine 4 partials
        const long long tot = redll[t] + redll[t + 64] + redll[t + 128] + redll[t + 192];
        const int g = t >> 5, d = t & 31;
        fs[g * IN_DIM + NODE_DIM + d] = ((float)tot * FXINV) / s_ecnt[g];
    } else if (t < 192) {  // u copy: 2 graphs x 64
        const int i = t - 64, g = i >> 6, c = i & 63;
        fs[g * IN_DIM + NODE_DIM + EDGE_DIM + c] = u[(size_t)(g0 + g) * GLOBAL_DIM + c];
    }
    __syncthreads();

    // ---- MLP ----
    float acc0, acc1;
    const float bb1 = b1[t];
    acc0 = acc1 = bb1;
    for (int k = 0; k < IN_DIM; ++k) {
        const float w = W1[k * HIDDEN_DIM + t];
        acc0 = fmaf(fs[k], w, acc0);
        acc1 = fmaf(fs[IN_DIM + k], w, acc1);
    }
    h[0][t] = fmaxf(acc0, 0.f); h[1][t] = fmaxf(acc1, 0.f);
    __syncthreads();

    const float bb2 = b2[t];
    acc0 = acc1 = bb2;
    for (int k = 0; k < HIDDEN_DIM; ++k) {
        const float w = W2[k * HIDDEN_DIM + t];
        acc0 = fmaf(h[0][k], w, acc0);
        acc1 = fmaf(h[1][k], w, acc1);
    }
    h2[0][t] = fmaxf(acc0, 0.f); h2[1][t] = fmaxf(acc1, 0.f);
    __syncthreads();

    // layer 3: 64 cols; thread t: col = t&63, k-quarter q = t>>6
    const int c3 = t & 63, q = t >> 6;
    acc0 = acc1 = 0.f;
    for (int k = q * 64; k < q * 64 + 64; ++k) {
        const float w = W3[k * GLOBAL_DIM + c3];
        acc0 = fmaf(h2[0][k], w, acc0);
        acc1 = fmaf(h2[1][k], w, acc1);
    }
    red[0][t] = acc0; red[1][t] = acc1;
    __syncthreads();
    if (t < GPB * GLOBAL_DIM) {
        const int g = t >> 6, c = t & 63;
        out[(size_t)(g0 + g) * GLOBAL_DIM + c] = red[g][c] + red[g][c + 64] +
                                                 red[g][c + 128] + red[g][c + 192] + b3[c];
    }
}

extern "C" void kernel_launch(void* const* d_in, const int* in_sizes, int n_in,
                              void* d_out, int out_size, void* d_ws, size_t ws_size,
                              hipStream_t stream) {
    const float* x         = (const float*)d_in[0];
    const int*   edge_idx  = (const int*)d_in[1];    // [2, E]; first E = sources
    const float* edge_attr = (const float*)d_in[2];
    const float* u         = (const float*)d_in[3];
    const int*   batch     = (const int*)d_in[4];
    const float* W1 = (const float*)d_in[5];
    const float* b1 = (const float*)d_in[6];
    const float* W2 = (const float*)d_in[7];
    const float* b2 = (const float*)d_in[8];
    const float* W3 = (const float*)d_in[9];
    const float* b3 = (const float*)d_in[10];
    float* out = (float*)d_out;

    int* ws32 = (int*)d_ws;
    int*            nstart = ws32 + WS_NSTART;
    float*          nsum   = (float*)(ws32 + WS_NSUM);
    int*            eslot  = ws32 + WS_ESLOT;
    unsigned short* seg    = (unsigned short*)(ws32 + WS_SEG);

    prep<<<SEG_BLKS + BND_BLKS, 256, 0, stream>>>(edge_idx, batch, seg, nstart);
    node_sum<<<N_GRAPHS, 256, 0, stream>>>(x, nstart, nsum);
    edge_scatter<<<EDGE_BLKS, 1024, 0, stream>>>(edge_attr, seg, eslot);
    finalize_mlp<<<N_GRAPHS / GPB, 256, 0, stream>>>(nsum, nstart, eslot, u,
                                                     W1, b1, W2, b2, W3, b3, out);
}

// Round 7
// 90.557 us; speedup vs baseline: 4.1106x; 1.1126x over previous
//
#include <hip/hip_runtime.h>
#include <hip/hip_bf16.h>

#define N_NODES    100000
#define N_EDGES    1600000
#define NODE_DIM   128
#define EDGE_DIM   32
#define GLOBAL_DIM 64
#define HIDDEN_DIM 256
#define N_GRAPHS   512
#define IN_DIM     224   // 128 + 32 + 64
#define ROW33      33    // 32 dims + count col; stride-33 spreads LDS banks

#define EDGE_BLKS  256                         // edge histogram blocks (1024 thr)
#define EDGE_CH    (N_EDGES / EDGE_BLKS)       // 6250
#define SEG_BLKS   ((N_EDGES / 4 + 255) / 256) // 1563
#define BND_BLKS   ((N_NODES + 255) / 256)     // 391
#define NSLOT      16                          // shared accumulator copies
#define SLOTSZ     (N_GRAPHS * ROW33)          // 16896 ints per slot
#define ZERO_BLKS  ((NSLOT * SLOTSZ / 4 + 255) / 256)  // 264 (int4 stores)
#define GPB        2                           // graphs per finalize+MLP block

// fixed-point scale for int32 accumulation (fp32 atomicAdd = CAS loop on HIP
// without -munsafe-fp-atomics — round-3/4 lesson: int atomics are native)
#define FXS   1048576.0f          // 2^20
#define FXINV (1.0f / 1048576.0f)

// ---------------- workspace layout (4-byte units) ----------------
#define WS_NSTART 0                                  // int[513] (pad 1024)
#define WS_NSUM   (WS_NSTART + 1024)                 // float[512*128]
#define WS_ESLOT  (WS_NSUM + N_GRAPHS * NODE_DIM)    // int[16*16896] — zeroed by prep
#define WS_SEG    (WS_ESLOT + NSLOT * SLOTSZ)        // ushort[1.6M]

// ---------------- prep: seg[] + node boundaries + zero eslot ---------------
__global__ __launch_bounds__(256) void prep(const int* __restrict__ eidx,
                                            const int* __restrict__ batch,
                                            unsigned short* __restrict__ seg,
                                            int* __restrict__ nstart,
                                            int4* __restrict__ eslot4) {
    const int blk = blockIdx.x;
    if (blk < SEG_BLKS) {
        const int base = (blk * 256 + threadIdx.x) * 4;
        if (base < N_EDGES) {
            const int4 e4 = *reinterpret_cast<const int4*>(eidx + base);
            ushort4 sv;
            sv.x = (unsigned short)batch[e4.x];
            sv.y = (unsigned short)batch[e4.y];
            sv.z = (unsigned short)batch[e4.z];
            sv.w = (unsigned short)batch[e4.w];
            *reinterpret_cast<ushort4*>(seg + base) = sv;
        }
    } else if (blk < SEG_BLKS + BND_BLKS) {
        const int i = (blk - SEG_BLKS) * 256 + threadIdx.x;
        if (i < N_NODES) {
            const int b0 = batch[i];
            if (i == 0)
                for (int g = 0; g <= b0; ++g) nstart[g] = 0;
            if (i < N_NODES - 1) {
                const int b1 = batch[i + 1];
                for (int g = b0 + 1; g <= b1; ++g) nstart[g] = i + 1;
            } else {
                for (int g = b0 + 1; g <= N_GRAPHS; ++g) nstart[g] = N_NODES;
            }
        }
    } else {
        const int i = (blk - SEG_BLKS - BND_BLKS) * 256 + threadIdx.x;
        if (i < NSLOT * SLOTSZ / 4) eslot4[i] = int4{0, 0, 0, 0};
    }
}

// ---------------- bulk: edge LDS histogram (256 blks) + node range-sum (512) --
__global__ __launch_bounds__(1024) void bulk(const float* __restrict__ eattr,
                                             const unsigned short* __restrict__ seg,
                                             const float* __restrict__ x,
                                             const int* __restrict__ nstart,
                                             int* __restrict__ eslot,
                                             float* __restrict__ nsum) {
    __shared__ int ssum[SLOTSZ];               // 67.6 KB (node path reuses as float2)
    const int t = threadIdx.x;

    if (blockIdx.x < EDGE_BLKS) {
        // ----- edge scatter-sum -----
        for (int i = t; i < SLOTSZ; i += 1024) ssum[i] = 0;
        __syncthreads();

        const int p = t & 7;                   // 8 lanes per 32-float edge row
        const int e1 = blockIdx.x * EDGE_CH + EDGE_CH;
#pragma unroll 4
        for (int e = blockIdx.x * EDGE_CH + (t >> 3); e < e1; e += 128) {
            const int s = seg[e];
            const float4 v = *reinterpret_cast<const float4*>(eattr + (size_t)e * EDGE_DIM + p * 4);
            const int b = s * ROW33 + p * 4;
            atomicAdd(&ssum[b + 0], __float2int_rn(v.x * FXS));
            atomicAdd(&ssum[b + 1], __float2int_rn(v.y * FXS));
            atomicAdd(&ssum[b + 2], __float2int_rn(v.z * FXS));
            atomicAdd(&ssum[b + 3], __float2int_rn(v.w * FXS));
            if (p == 0) atomicAdd(&ssum[s * ROW33 + 32], 1);
        }
        __syncthreads();

        // flush into 1 of 16 shared slots (native int atomics, fire-and-forget)
        int* gs = eslot + (size_t)(blockIdx.x & (NSLOT - 1)) * SLOTSZ;
        for (int i = t; i < SLOTSZ; i += 1024) {
            const int v = ssum[i];
            if (v) atomicAdd(gs + i, v);
        }
    } else {
        // ----- node range-sum: one block per graph, float2, 16 rows in flight -----
        const int g = blockIdx.x - EDGE_BLKS;
        const int dp = t & 63;                 // float2 dim-pair: dims 2dp, 2dp+1
        const int off = t >> 6;                // row offset 0..15
        const int s0 = nstart[g], e0 = nstart[g + 1];

        float ax0 = 0.f, ay0 = 0.f, ax1 = 0.f, ay1 = 0.f;
        float ax2 = 0.f, ay2 = 0.f, ax3 = 0.f, ay3 = 0.f;
        int r = s0 + off;
        for (; r + 48 < e0; r += 64) {
            const float2 v0 = *reinterpret_cast<const float2*>(x + (size_t)(r     ) * NODE_DIM + dp * 2);
            const float2 v1 = *reinterpret_cast<const float2*>(x + (size_t)(r + 16) * NODE_DIM + dp * 2);
            const float2 v2 = *reinterpret_cast<const float2*>(x + (size_t)(r + 32) * NODE_DIM + dp * 2);
            const float2 v3 = *reinterpret_cast<const float2*>(x + (size_t)(r + 48) * NODE_DIM + dp * 2);
            ax0 += v0.x; ay0 += v0.y; ax1 += v1.x; ay1 += v1.y;
            ax2 += v2.x; ay2 += v2.y; ax3 += v3.x; ay3 += v3.y;
        }
        for (; r < e0; r += 16) {
            const float2 v = *reinterpret_cast<const float2*>(x + (size_t)r * NODE_DIM + dp * 2);
            ax0 += v.x; ay0 += v.y;
        }

        float2* part2 = reinterpret_cast<float2*>(ssum);   // 1024 float2 = 8 KB
        part2[t] = float2{(ax0 + ax1) + (ax2 + ax3), (ay0 + ay1) + (ay2 + ay3)};
        __syncthreads();
        if (t < 64) {
            float sx = 0.f, sy = 0.f;
#pragma unroll 16
            for (int k = 0; k < 16; ++k) {
                const float2 v = part2[t + 64 * k];
                sx += v.x; sy += v.y;
            }
            reinterpret_cast<float2*>(nsum)[(size_t)g * 64 + t] = float2{sx, sy};
        }
    }
}

// ---------------- finalize + MLP fused: GPB graphs per block ---------------
__global__ __launch_bounds__(256) void finalize_mlp(const float* __restrict__ nsum,
                                                    const int* __restrict__ nstart,
                                                    const int* __restrict__ eslot,
                                                    const float* __restrict__ u,
                                                    const float* __restrict__ W1, const float* __restrict__ b1,
                                                    const float* __restrict__ W2, const float* __restrict__ b2,
                                                    const float* __restrict__ W3, const float* __restrict__ b3,
                                                    float* __restrict__ out) {
    const int g0 = blockIdx.x * GPB;
    const int t = threadIdx.x;
    __shared__ float fs[GPB * IN_DIM];
    __shared__ long long redll[256];
    __shared__ float h[GPB][HIDDEN_DIM];
    __shared__ float h2[GPB][HIDDEN_DIM];
    __shared__ float red[GPB][256];
    __shared__ float s_ecnt[GPB];

    // edge dim partials: col = t&63 (g = col>>5, d = col&31), part = t>>6 over 4x4 slots
    {
        const int col = t & 63, part = t >> 6;
        const int g = col >> 5, d = col & 31;
        long long s = 0;
#pragma unroll 4
        for (int sl = part * 4; sl < part * 4 + 4; ++sl)
            s += eslot[(size_t)sl * SLOTSZ + (size_t)(g0 + g) * ROW33 + d];
        redll[t] = s;
    }
    if (t < GPB) {  // edge counts: scan 16 slots' count col
        int c = 0;
#pragma unroll 16
        for (int sl = 0; sl < NSLOT; ++sl)
            c += eslot[(size_t)sl * SLOTSZ + (size_t)(g0 + t) * ROW33 + 32];
        s_ecnt[t] = fmaxf((float)c, 1.f);
    }
    __syncthreads();

    {   // node means: 2 graphs x 128 dims = 256 -> one per thread
        const int g = t >> 7, d = t & 127;
        const float cnt = fmaxf((float)(nstart[g0 + g + 1] - nstart[g0 + g]), 1.f);
        fs[g * IN_DIM + d] = nsum[(size_t)(g0 + g) * NODE_DIM + d] / cnt;
    }
    if (t < 64) {   // edge means: combine 4 partials
        const long long tot = redll[t] + redll[t + 64] + redll[t + 128] + redll[t + 192];
        const int g = t >> 5, d = t & 31;
        fs[g * IN_DIM + NODE_DIM + d] = ((float)tot * FXINV) / s_ecnt[g];
    } else if (t < 192) {  // u copy: 2 graphs x 64
        const int i = t - 64, g = i >> 6, c = i & 63;
        fs[g * IN_DIM + NODE_DIM + EDGE_DIM + c] = u[(size_t)(g0 + g) * GLOBAL_DIM + c];
    }
    __syncthreads();

    // ---- MLP ----
    float acc0, acc1;
    const float bb1 = b1[t];
    acc0 = acc1 = bb1;
    for (int k = 0; k < IN_DIM; ++k) {
        const float w = W1[k * HIDDEN_DIM + t];
        acc0 = fmaf(fs[k], w, acc0);
        acc1 = fmaf(fs[IN_DIM + k], w, acc1);
    }
    h[0][t] = fmaxf(acc0, 0.f); h[1][t] = fmaxf(acc1, 0.f);
    __syncthreads();

    const float bb2 = b2[t];
    acc0 = acc1 = bb2;
    for (int k = 0; k < HIDDEN_DIM; ++k) {
        const float w = W2[k * HIDDEN_DIM + t];
        acc0 = fmaf(h[0][k], w, acc0);
        acc1 = fmaf(h[1][k], w, acc1);
    }
    h2[0][t] = fmaxf(acc0, 0.f); h2[1][t] = fmaxf(acc1, 0.f);
    __syncthreads();

    const int c3 = t & 63, q = t >> 6;
    acc0 = acc1 = 0.f;
    for (int k = q * 64; k < q * 64 + 64; ++k) {
        const float w = W3[k * GLOBAL_DIM + c3];
        acc0 = fmaf(h2[0][k], w, acc0);
        acc1 = fmaf(h2[1][k], w, acc1);
    }
    red[0][t] = acc0; red[1][t] = acc1;
    __syncthreads();
    if (t < GPB * GLOBAL_DIM) {
        const int g = t >> 6, c = t & 63;
        out[(size_t)(g0 + g) * GLOBAL_DIM + c] = red[g][c] + red[g][c + 64] +
                                                 red[g][c + 128] + red[g][c + 192] + b3[c];
    }
}

extern "C" void kernel_launch(void* const* d_in, const int* in_sizes, int n_in,
                              void* d_out, int out_size, void* d_ws, size_t ws_size,
                              hipStream_t stream) {
    const float* x         = (const float*)d_in[0];
    const int*   edge_idx  = (const int*)d_in[1];    // [2, E]; first E = sources
    const float* edge_attr = (const float*)d_in[2];
    const float* u         = (const float*)d_in[3];
    const int*   batch     = (const int*)d_in[4];
    const float* W1 = (const float*)d_in[5];
    const float* b1 = (const float*)d_in[6];
    const float* W2 = (const float*)d_in[7];
    const float* b2 = (const float*)d_in[8];
    const float* W3 = (const float*)d_in[9];
    const float* b3 = (const float*)d_in[10];
    float* out = (float*)d_out;

    int* ws32 = (int*)d_ws;
    int*            nstart = ws32 + WS_NSTART;
    float*          nsum   = (float*)(ws32 + WS_NSUM);
    int*            eslot  = ws32 + WS_ESLOT;
    unsigned short* seg    = (unsigned short*)(ws32 + WS_SEG);

    prep<<<SEG_BLKS + BND_BLKS + ZERO_BLKS, 256, 0, stream>>>(edge_idx, batch, seg, nstart,
                                                              (int4*)eslot);
    bulk<<<EDGE_BLKS + N_GRAPHS, 1024, 0, stream>>>(edge_attr, seg, x, nstart, eslot, nsum);
    finalize_mlp<<<N_GRAPHS / GPB, 256, 0, stream>>>(nsum, nstart, eslot, u,
                                                     W1, b1, W2, b2, W3, b3, out);
}